// Round 6
// baseline (161.993 us; speedup 1.0000x reference)
//
#include <hip/hip_runtime.h>
#include <math.h>

#define TAU 32.0f
#define LO_SCALE 2048.0f
#define INV_LO_SCALE (1.0f/2048.0f)

typedef _Float16 f16x8 __attribute__((ext_vector_type(8)));
typedef float    f32x16 __attribute__((ext_vector_type(16)));

// ---------------------------------------------------------------------------
// Kernel 1: MW[n][k] = sum_e M[n%90][e] * W[e][k], n<90 -> W_topic else W_domain.
// Output as f16 hi + f16 scaled-lo (lo*2048) into ws: exactly 180*768*2*2B.
// ---------------------------------------------------------------------------
__global__ __launch_bounds__(256) void precompute_mw(
    const float* __restrict__ Wt, const float* __restrict__ Wd,
    const float* __restrict__ dmem, _Float16* __restrict__ MWhi,
    _Float16* __restrict__ MWlo)
{
    __shared__ float Ml[3 * 768];
    const int nt = blockIdx.x;   // 0..59
    const int kc = blockIdx.y;   // 0..2
    const int n0 = nt * 3;
    const float* __restrict__ W = (n0 < 90) ? Wt : Wd;
    const int m0 = (n0 < 90) ? n0 : n0 - 90;
    for (int idx = threadIdx.x; idx < 3 * 768; idx += 256)
        Ml[idx] = dmem[m0 * 768 + idx];
    __syncthreads();
    const int k = kc * 256 + threadIdx.x;
    float a0 = 0.f, a1 = 0.f, a2 = 0.f;
    #pragma unroll 4
    for (int e = 0; e < 768; ++e) {
        const float w = W[e * 768 + k];
        a0 = fmaf(Ml[e],        w, a0);
        a1 = fmaf(Ml[768 + e],  w, a1);
        a2 = fmaf(Ml[1536 + e], w, a2);
    }
    float v[3] = {a0, a1, a2};
    #pragma unroll
    for (int i = 0; i < 3; ++i) {
        _Float16 h = (_Float16)v[i];
        float lo = (v[i] - (float)h) * LO_SCALE;
        MWhi[(n0 + i) * 768 + k] = h;
        MWlo[(n0 + i) * 768 + k] = (_Float16)lo;
    }
}

// ---------------------------------------------------------------------------
// Kernel 2: pipelined split-f16 MFMA GEMM + fused softmax chain.
// Round-5 was latency-bound (MfmaUtil 11%, all pipes idle): B loads issued at
// point of use, 2 barriers/iter. Now: A LDS double-buffered (1 barrier/iter),
// B register-prefetched one half-K ahead (3 half-sets live, +72 VGPR),
// F prefetched 2 iterations ahead (covers ~900cyc HBM latency).
// ---------------------------------------------------------------------------

#define LOADB(DH, DL, T, KS) do {                                          \
    const int _kk = (T) * 32 + (KS) * 16;                                  \
    _Pragma("unroll")                                                      \
    for (int _nt = 0; _nt < 3; ++_nt) {                                    \
        DH[_nt] = *(const f16x8*)(MWhi + bofs[_nt] + _kk);                 \
        DL[_nt] = *(const f16x8*)(MWlo + bofs[_nt] + _kk);                 \
    }                                                                      \
} while (0)

#define MFMA_K(BUF, KS, BH, BL) do {                                       \
    const int _ao = (arow * 64 + (KS) * 32 + asel) ^ swzA;                 \
    f16x8 _ah = *(const f16x8*)((const char*)AhL[BUF] + _ao);              \
    f16x8 _al = *(const f16x8*)((const char*)AlL[BUF] + _ao);              \
    _Pragma("unroll")                                                      \
    for (int _nt = 0; _nt < 3; ++_nt) {                                    \
        acc1[_nt] = __builtin_amdgcn_mfma_f32_32x32x16_f16(_ah, BH[_nt], acc1[_nt], 0, 0, 0); \
        acc2[_nt] = __builtin_amdgcn_mfma_f32_32x32x16_f16(_ah, BL[_nt], acc2[_nt], 0, 0, 0); \
        acc2[_nt] = __builtin_amdgcn_mfma_f32_32x32x16_f16(_al, BH[_nt], acc2[_nt], 0, 0, 0); \
    }                                                                      \
} while (0)

#define CONVERT_STORE(Q0, Q1, BUF) do {                                    \
    f16x8 _h8, _l8;                                                        \
    float _xs[8] = {Q0.x, Q0.y, Q0.z, Q0.w, Q1.x, Q1.y, Q1.z, Q1.w};       \
    _Pragma("unroll")                                                      \
    for (int _i = 0; _i < 8; ++_i) {                                       \
        float _x = _xs[_i];                                                \
        _Float16 _hh = (_Float16)_x;                                       \
        _h8[_i] = _hh;                                                     \
        _l8[_i] = (_Float16)((_x - (float)_hh) * LO_SCALE);                \
        ps += _x * _x;                                                     \
    }                                                                      \
    *(f16x8*)((char*)AhL[BUF] + wb) = _h8;                                 \
    *(f16x8*)((char*)AlL[BUF] + wb) = _l8;                                 \
} while (0)

__global__ __launch_bounds__(256, 1) void fused_memnet(
    const float* __restrict__ F, const _Float16* __restrict__ MWhi,
    const _Float16* __restrict__ MWlo, float* __restrict__ out)
{
    __shared__ alignas(16) _Float16 AhL[2][64 * 32];  // 8 KB double-buffered
    __shared__ alignas(16) _Float16 AlL[2][64 * 32];  // 8 KB
    __shared__ float raw[64 * 196];                   // 50.2 KB epilogue
    __shared__ float ss[64];

    const int tid  = threadIdx.x;
    const int lane = tid & 63;
    const int wid  = tid >> 6;
    const int wrow = (wid >> 1) * 32;
    const int wcol = (wid & 1) * 96;
    const int row0 = blockIdx.x * 64;

    // staging ids
    const int srow = tid >> 2;        // 0..63
    const int sc   = tid & 3;         // 16B chunk within k-window
    const float* __restrict__ Fp = F + (row0 + srow) * 768 + sc * 8;
    const int wb = (srow * 64 + sc * 16) ^ ((srow & 7) << 4);

    // B fragment offsets (rows >179 clamped; pad cols unused by epilogue)
    int bofs[3];
    #pragma unroll
    for (int nt = 0; nt < 3; ++nt) {
        int brow = wcol + nt * 32 + (lane & 31);
        if (brow > 179) brow = 179;
        bofs[nt] = brow * 768 + (lane >> 5) * 8;
    }

    // A fragment read addressing
    const int arow = wrow + (lane & 31);
    const int swzA = (arow & 7) << 4;
    const int asel = (lane >> 5) * 16;

    f32x16 acc1[3], acc2[3];
    #pragma unroll
    for (int nt = 0; nt < 3; ++nt)
        #pragma unroll
        for (int r = 0; r < 16; ++r) { acc1[nt][r] = 0.f; acc2[nt][r] = 0.f; }

    float ps = 0.f;

    // ---- prologue: F[0] -> buf0; F[1],F[2] in flight; B[0] both half-K sets
    float4 z0  = *(const float4*)(Fp);
    float4 z1  = *(const float4*)(Fp + 4);
    float4 fA0 = *(const float4*)(Fp + 32);
    float4 fA1 = *(const float4*)(Fp + 36);
    float4 fB0 = *(const float4*)(Fp + 64);
    float4 fB1 = *(const float4*)(Fp + 68);
    f16x8 C0h[3], C0l[3], C1h[3], C1l[3];
    f16x8 N0h[3], N0l[3], N1h[3], N1l[3];
    LOADB(C0h, C0l, 0, 0);
    LOADB(C1h, C1l, 0, 1);
    CONVERT_STORE(z0, z1, 0);
    __syncthreads();

    for (int t = 0; t < 24; t += 2) {
        // ---- even body: MFMA buf0 with C sets; prefetch B[t+1] -> N; A[t+1] -> buf1
        if (t < 23) LOADB(N0h, N0l, t + 1, 0);
        MFMA_K(0, 0, C0h, C0l);
        if (t < 23) LOADB(N1h, N1l, t + 1, 1);
        MFMA_K(0, 1, C1h, C1l);
        if (t < 23) CONVERT_STORE(fA0, fA1, 1);
        if (t < 21) {
            fA0 = *(const float4*)(Fp + (t + 3) * 32);
            fA1 = *(const float4*)(Fp + (t + 3) * 32 + 4);
        }
        __syncthreads();
        // ---- odd body: MFMA buf1 with N sets; prefetch B[t+2] -> C; A[t+2] -> buf0
        if (t + 1 < 23) LOADB(C0h, C0l, t + 2, 0);
        MFMA_K(1, 0, N0h, N0l);
        if (t + 1 < 23) LOADB(C1h, C1l, t + 2, 1);
        MFMA_K(1, 1, N1h, N1l);
        if (t + 1 < 23) CONVERT_STORE(fB0, fB1, 0);
        if (t + 1 < 21) {
            fB0 = *(const float4*)(Fp + (t + 4) * 32);
            fB1 = *(const float4*)(Fp + (t + 4) * 32 + 4);
        }
        __syncthreads();
    }

    // ---- row sum-of-squares: 4 staging threads per row
    ps += __shfl_xor(ps, 1);
    ps += __shfl_xor(ps, 2);
    if (sc == 0) ss[srow] = ps;

    // ---- write raw scores (verified 32x32 C/D layout:
    //      col=lane&31, row=(reg&3)+8*(reg>>2)+4*(lane>>5))
    #pragma unroll
    for (int nt = 0; nt < 3; ++nt) {
        const int cl = wcol + nt * 32 + (lane & 31);
        #pragma unroll
        for (int r = 0; r < 16; ++r) {
            const int rl = wrow + (r & 3) + 8 * (r >> 2) + 4 * (lane >> 5);
            raw[rl * 196 + cl] = acc1[nt][r] + acc2[nt][r] * INV_LO_SCALE;
        }
    }
    __syncthreads();

    // ---- softmax chain, one thread per row
    if (tid < 64) {
        const int r = tid;
        const float s = TAU / sqrtf(ss[r]);       // TAU / ||f||
        const float* Sr = raw + r * 196;
        float logit[9];
        #pragma unroll
        for (int d = 0; d < 9; ++d) {
            float vv[10];
            float mx = -1e30f;
            #pragma unroll
            for (int m = 0; m < 10; ++m) {
                vv[m] = s * Sr[d * 10 + m];
                mx = fmaxf(mx, vv[m]);
            }
            float den = 0.f, num = 0.f;
            #pragma unroll
            for (int m = 0; m < 10; ++m) {
                const float e = expf(vv[m] - mx);
                den += e;
                num = fmaf(e, Sr[90 + d * 10 + m], num);
            }
            logit[d] = s * num / den;             // TAU * (sep_emb . q_dom)
        }
        float mx2 = -1e30f;
        #pragma unroll
        for (int d = 0; d < 9; ++d) mx2 = fmaxf(mx2, logit[d]);
        float e2[9], den2 = 0.f;
        #pragma unroll
        for (int d = 0; d < 9; ++d) { e2[d] = expf(logit[d] - mx2); den2 += e2[d]; }
        const float inv = 1.f / den2;
        float* op = out + (row0 + r) * 9;
        #pragma unroll
        for (int d = 0; d < 9; ++d) op[d] = e2[d] * inv;
    }
}

// ---------------------------------------------------------------------------
extern "C" void kernel_launch(void* const* d_in, const int* in_sizes, int n_in,
                              void* d_out, int out_size, void* d_ws, size_t ws_size,
                              hipStream_t stream)
{
    const float* feature = (const float*)d_in[0];
    // d_in[1] = category (int64) — unused by the reference computation
    const float* Wt   = (const float*)d_in[2];
    const float* Wd   = (const float*)d_in[3];
    const float* dmem = (const float*)d_in[4];
    float* outp = (float*)d_out;
    _Float16* MWhi = (_Float16*)d_ws;            // 180*768 f16
    _Float16* MWlo = MWhi + 180 * 768;           // total 552,960 B (fits ws)

    precompute_mw<<<dim3(60, 3), 256, 0, stream>>>(Wt, Wd, dmem, MWhi, MWlo);
    fused_memnet<<<32768 / 64, 256, 0, stream>>>(feature, MWhi, MWlo, outp);
}